// Round 1
// baseline (371.886 us; speedup 1.0000x reference)
//
#include <hip/hip_runtime.h>

#define DEV __device__ __forceinline__

typedef __attribute__((ext_vector_type(8))) short short8v;
typedef __attribute__((ext_vector_type(4))) float f32x4;

DEV unsigned short f2bf(float f) {
  unsigned int x = __float_as_uint(f);
  x = x + 0x7FFFu + ((x >> 16) & 1u);   // RNE
  return (unsigned short)(x >> 16);
}

// ---- swizzled LDS tile: 128 rows x 64 bf16 (128 B/row, 8x16B chunks) ----
// chunk index XORed with (row&7): kills the stride-128B bank conflict on
// ds_read_b128 (G4) while keeping 16B alignment on reads, 8B on writes.
DEV int swz_byte(int row, int kElem) {
  int chunk = ((kElem >> 3) ^ (row & 7));
  return row * 128 + (chunk << 4) + ((kElem & 7) << 1);
}

// Stage a 128x64 tile (rows rowBase.., cols kBase..kBase+63) into LDS as bf16.
// T = float (convert) or unsigned short (already bf16). 256 threads.
template <typename T>
DEV void stage_tile(const T* __restrict__ g, int rowBase, int ld, int kBase,
                    unsigned short* tile, int tid) {
  const int rl = tid >> 4;          // 0..15
  const int c4 = (tid & 15) << 2;   // 0,4,...,60
#pragma unroll
  for (int p = 0; p < 8; ++p) {
    const int row = (p << 4) + rl;
    const T* src = g + (long)(rowBase + row) * ld + kBase + c4;
    unsigned short u0, u1, u2, u3;
    if constexpr (sizeof(T) == 4) {
      const float4 f = *reinterpret_cast<const float4*>(src);
      u0 = f2bf(f.x); u1 = f2bf(f.y); u2 = f2bf(f.z); u3 = f2bf(f.w);
    } else {
      const ushort4 s = *reinterpret_cast<const ushort4*>(src);
      u0 = s.x; u1 = s.y; u2 = s.z; u3 = s.w;
    }
    ushort4 pack; pack.x = u0; pack.y = u1; pack.z = u2; pack.w = u3;
    *reinterpret_cast<ushort4*>(reinterpret_cast<char*>(tile) + swz_byte(row, c4)) = pack;
  }
}

// NT GEMM: C[M][N] = A[M][K] * B[N][K]^T, lda=ldb=K, ldc=N, batched via z.
// EPI: 0 -> store bf16, 1 -> store f32, 2 -> store f32 with scale + mask.
template <typename TA, typename TB, int EPI>
__global__ __launch_bounds__(256) void gemm_nt(
    const TA* __restrict__ A, const TB* __restrict__ B, void* __restrict__ Cout,
    int M, int N, int K,
    long aBatch, long bBatch, long cBatch,
    const int* __restrict__ srcMask, const int* __restrict__ melMask,
    float scale) {
  __shared__ unsigned short As[128 * 64];
  __shared__ unsigned short Bs[128 * 64];
  const int tid = threadIdx.x;
  const int lane = tid & 63;
  const int wave = tid >> 6;
  const int z = blockIdx.z;
  const TA* Ab = A + (long)z * aBatch;
  const TB* Bb = B + (long)z * bBatch;
  const long cOff = (long)z * cBatch;
  const int bm = blockIdx.y * 128;
  const int bn = blockIdx.x * 128;
  const int wr = (wave >> 1) * 64;
  const int wc = (wave & 1) * 64;
  const int l15 = lane & 15;
  const int lHi = lane >> 4;

  f32x4 acc[4][4] = {};

  for (int kt = 0; kt < K; kt += 64) {
    stage_tile<TA>(Ab, bm, K, kt, As, tid);
    stage_tile<TB>(Bb, bn, K, kt, Bs, tid);
    __syncthreads();
#pragma unroll
    for (int ks = 0; ks < 2; ++ks) {
      const int k0 = (ks << 5) + (lHi << 3);
      short8v af[4], bfr[4];
#pragma unroll
      for (int i = 0; i < 4; ++i)
        af[i] = *reinterpret_cast<const short8v*>(
            reinterpret_cast<const char*>(As) + swz_byte(wr + i * 16 + l15, k0));
#pragma unroll
      for (int j = 0; j < 4; ++j)
        bfr[j] = *reinterpret_cast<const short8v*>(
            reinterpret_cast<const char*>(Bs) + swz_byte(wc + j * 16 + l15, k0));
#pragma unroll
      for (int i = 0; i < 4; ++i)
#pragma unroll
        for (int j = 0; j < 4; ++j)
          acc[i][j] = __builtin_amdgcn_mfma_f32_16x16x32_bf16(af[i], bfr[j], acc[i][j], 0, 0, 0);
    }
    __syncthreads();
  }

#pragma unroll
  for (int i = 0; i < 4; ++i) {
#pragma unroll
    for (int j = 0; j < 4; ++j) {
      const int rb = bm + wr + i * 16 + lHi * 4;
      const int c = bn + wc + j * 16 + l15;
#pragma unroll
      for (int r = 0; r < 4; ++r) {
        const float v = acc[i][j][r];
        const long idx = cOff + (long)(rb + r) * N + c;
        if constexpr (EPI == 0) {
          reinterpret_cast<unsigned short*>(Cout)[idx] = f2bf(v);
        } else if constexpr (EPI == 1) {
          reinterpret_cast<float*>(Cout)[idx] = v;
        } else {
          const bool sm = srcMask[z * 1024 + (rb + r)] != 0;
          const bool mm = melMask[z * 2048 + c] != 0;
          reinterpret_cast<float*>(Cout)[idx] = (sm && mm) ? -1e30f : v * scale;
        }
      }
    }
  }
}

// Transpose+convert the three 512x512 fp32 weights to bf16 W^T.
__global__ __launch_bounds__(256) void transpose_w3(
    const float* __restrict__ Wq, const float* __restrict__ Wk, const float* __restrict__ Wv,
    unsigned short* __restrict__ WqT, unsigned short* __restrict__ WkT,
    unsigned short* __restrict__ WvT) {
  __shared__ float t[32][33];
  const int zz = blockIdx.z;
  const float* W = zz == 0 ? Wq : zz == 1 ? Wk : Wv;
  unsigned short* WT = zz == 0 ? WqT : zz == 1 ? WkT : WvT;
  const int bx = blockIdx.x * 32;  // m base (output row)
  const int by = blockIdx.y * 32;  // d base (output col)
  const int tx = threadIdx.x, ty = threadIdx.y;  // (32,8)
#pragma unroll
  for (int i = 0; i < 4; ++i)
    t[ty + i * 8][tx] = W[(long)(by + ty + i * 8) * 512 + bx + tx];
  __syncthreads();
#pragma unroll
  for (int i = 0; i < 4; ++i)
    WT[(long)(bx + ty + i * 8) * 512 + by + tx] = f2bf(t[tx][ty + i * 8]);
}

// In-place softmax over rows of 2048 fp32 (masked entries hold -1e30).
__global__ __launch_bounds__(256) void softmax_rows(float* __restrict__ attn) {
  const long row = blockIdx.x;
  float4* p = reinterpret_cast<float4*>(attn + row * 2048);
  const int tid = threadIdx.x;
  float4 a = p[tid];
  float4 b = p[tid + 256];
  float m = fmaxf(fmaxf(fmaxf(a.x, a.y), fmaxf(a.z, a.w)),
                  fmaxf(fmaxf(b.x, b.y), fmaxf(b.z, b.w)));
#pragma unroll
  for (int o = 32; o; o >>= 1) m = fmaxf(m, __shfl_xor(m, o, 64));
  __shared__ float redm[4];
  if ((tid & 63) == 0) redm[tid >> 6] = m;
  __syncthreads();
  m = fmaxf(fmaxf(redm[0], redm[1]), fmaxf(redm[2], redm[3]));
  float e0 = __expf(a.x - m), e1 = __expf(a.y - m), e2 = __expf(a.z - m), e3 = __expf(a.w - m);
  float e4 = __expf(b.x - m), e5 = __expf(b.y - m), e6 = __expf(b.z - m), e7 = __expf(b.w - m);
  float s = ((e0 + e1) + (e2 + e3)) + ((e4 + e5) + (e6 + e7));
#pragma unroll
  for (int o = 32; o; o >>= 1) s += __shfl_xor(s, o, 64);
  __shared__ float reds[4];
  if ((tid & 63) == 0) reds[tid >> 6] = s;
  __syncthreads();
  s = (reds[0] + reds[1]) + (reds[2] + reds[3]);
  const float inv = 1.0f / s;
  a.x = e0 * inv; a.y = e1 * inv; a.z = e2 * inv; a.w = e3 * inv;
  b.x = e4 * inv; b.y = e5 * inv; b.z = e6 * inv; b.w = e7 * inv;
  p[tid] = a;
  p[tid + 256] = b;
}

// In-place LayerNorm over rows of 512 fp32. One wave per row.
__global__ __launch_bounds__(64) void layernorm_rows(
    float* __restrict__ out, const float* __restrict__ gamma, const float* __restrict__ beta) {
  const long row = blockIdx.x;
  float4* p = reinterpret_cast<float4*>(out + row * 512);
  const int lane = threadIdx.x;
  float4 a = p[lane];
  float4 b = p[lane + 64];
  float s = ((a.x + a.y) + (a.z + a.w)) + ((b.x + b.y) + (b.z + b.w));
  float s2 = ((a.x * a.x + a.y * a.y) + (a.z * a.z + a.w * a.w)) +
             ((b.x * b.x + b.y * b.y) + (b.z * b.z + b.w * b.w));
#pragma unroll
  for (int o = 32; o; o >>= 1) {
    s += __shfl_xor(s, o, 64);
    s2 += __shfl_xor(s2, o, 64);
  }
  const float mean = s * (1.0f / 512.0f);
  const float var = s2 * (1.0f / 512.0f) - mean * mean;
  const float rstd = rsqrtf(var + 1e-5f);
  const float4 g0 = reinterpret_cast<const float4*>(gamma)[lane];
  const float4 g1 = reinterpret_cast<const float4*>(gamma)[lane + 64];
  const float4 c0 = reinterpret_cast<const float4*>(beta)[lane];
  const float4 c1 = reinterpret_cast<const float4*>(beta)[lane + 64];
  a.x = (a.x - mean) * rstd * g0.x + c0.x;
  a.y = (a.y - mean) * rstd * g0.y + c0.y;
  a.z = (a.z - mean) * rstd * g0.z + c0.z;
  a.w = (a.w - mean) * rstd * g0.w + c0.w;
  b.x = (b.x - mean) * rstd * g1.x + c1.x;
  b.y = (b.y - mean) * rstd * g1.y + c1.y;
  b.z = (b.z - mean) * rstd * g1.z + c1.z;
  b.w = (b.w - mean) * rstd * g1.w + c1.w;
  p[lane] = a;
  p[lane + 64] = b;
}

extern "C" void kernel_launch(void* const* d_in, const int* in_sizes, int n_in,
                              void* d_out, int out_size, void* d_ws, size_t ws_size,
                              hipStream_t stream) {
  const float* mel  = (const float*)d_in[0];   // [16,2048,512]
  const float* text = (const float*)d_in[1];   // [16,1024,512]
  const int* melMask = (const int*)d_in[2];    // [16,2048]
  const int* srcMask = (const int*)d_in[3];    // [16,1024]
  const float* Wq = (const float*)d_in[4];     // [512,512]
  const float* Wk = (const float*)d_in[5];
  const float* Wv = (const float*)d_in[6];
  const float* gamma = (const float*)d_in[7];  // [512]
  const float* beta  = (const float*)d_in[8];

  float* out = (float*)d_out;                           // [16,1024,512]
  float* attn = (float*)d_out + (long)16 * 1024 * 512;  // [16,1024,2048]

  unsigned short* ws = (unsigned short*)d_ws;
  unsigned short* wqT = ws;                                 // 512*512
  unsigned short* wkT = wqT + 512 * 512;
  unsigned short* wvT = wkT + 512 * 512;
  unsigned short* qbf = wvT + 512 * 512;                    // [16*1024,512]
  unsigned short* kbf = qbf + (long)16 * 1024 * 512;        // [16*2048,512]
  unsigned short* vT  = kbf + (long)16 * 2048 * 512;        // [16][512][2048]

  // 1) W^T (bf16) for all three projections
  transpose_w3<<<dim3(16, 16, 3), dim3(32, 8), 0, stream>>>(Wq, Wk, Wv, wqT, wkT, wvT);

  // 2) q = text @ Wq  (NT: B = Wq^T), bf16 out
  gemm_nt<float, unsigned short, 0><<<dim3(4, 128, 1), 256, 0, stream>>>(
      text, wqT, qbf, 16384, 512, 512, 0, 0, 0, nullptr, nullptr, 1.0f);

  // 3) k = mel @ Wk, bf16 out
  gemm_nt<float, unsigned short, 0><<<dim3(4, 256, 1), 256, 0, stream>>>(
      mel, wkT, kbf, 32768, 512, 512, 0, 0, 0, nullptr, nullptr, 1.0f);

  // 4) vT[b][m][s] = sum_d Wv[d][m]*mel[b][s][d]  (NT: A = Wv^T, B = mel[b])
  gemm_nt<unsigned short, float, 0><<<dim3(16, 4, 16), 256, 0, stream>>>(
      wvT, mel, vT, 512, 2048, 512, 0, (long)2048 * 512, (long)512 * 2048,
      nullptr, nullptr, 1.0f);

  // 5) raw masked scores -> attn region (fp32)
  gemm_nt<unsigned short, unsigned short, 2><<<dim3(16, 8, 16), 256, 0, stream>>>(
      qbf, kbf, attn, 1024, 2048, 512,
      (long)1024 * 512, (long)2048 * 512, (long)1024 * 2048,
      srcMask, melMask, 0.044194173824159216f);

  // 6) softmax rows in place
  softmax_rows<<<dim3(16 * 1024), 256, 0, stream>>>(attn);

  // 7) out = attn @ v  (NT: B = vT[b])
  gemm_nt<float, unsigned short, 1><<<dim3(4, 8, 16), 256, 0, stream>>>(
      attn, vT, out, 1024, 512, 2048,
      (long)1024 * 2048, (long)512 * 2048, (long)1024 * 512,
      nullptr, nullptr, 1.0f);

  // 8) LayerNorm rows in place
  layernorm_rows<<<dim3(16 * 1024), 64, 0, stream>>>(out, gamma, beta);
}

// Round 2
// 309.498 us; speedup vs baseline: 1.2016x; 1.2016x over previous
//
#include <hip/hip_runtime.h>

#define DEV __device__ __forceinline__

typedef __attribute__((ext_vector_type(8))) short short8v;
typedef __attribute__((ext_vector_type(4))) float f32x4;

DEV unsigned short f2bf(float f) {
  unsigned int x = __float_as_uint(f);
  x = x + 0x7FFFu + ((x >> 16) & 1u);   // RNE
  return (unsigned short)(x >> 16);
}

// ---- swizzled LDS tile: R rows x 64 bf16 (128 B/row, 8x16B chunks) ----
// LDS chunk c of row r holds global chunk c ^ (r&7)  (involution).
DEV int swz_byte(int row, int kElem) {
  int chunk = ((kElem >> 3) ^ (row & 7));
  return row * 128 + (chunk << 4) + ((kElem & 7) << 1);
}

// Stage ROUNDS*32 rows x 64 cols of bf16 from g (row stride ld elements) into
// swizzled LDS tile. global_load_lds: linear LDS dest (wave-uniform base +
// lane*16), pre-swizzled global source; both sides use the same involution.
template <int ROUNDS>
DEV void stage(const unsigned short* __restrict__ g, int ld,
               unsigned short* tile, int tid) {
  const int wave = tid >> 6, l = tid & 63;
#pragma unroll
  for (int p = 0; p < ROUNDS; ++p) {
    const int r = (p << 5) + (wave << 3) + (l >> 3);     // row 0..ROUNDS*32-1
    const int c = ((l & 7) ^ (r & 7)) << 3;              // pre-swizzled col
    const unsigned short* src = g + (long)r * ld + c;
#if __has_builtin(__builtin_amdgcn_global_load_lds)
    unsigned short* dst = tile + (p << 11) + (wave << 9);  // wave-uniform
    __builtin_amdgcn_global_load_lds(
        (const __attribute__((address_space(1))) void*)src,
        (__attribute__((address_space(3))) void*)dst, 16, 0, 0);
#else
    short8v v = *reinterpret_cast<const short8v*>(src);
    *reinterpret_cast<short8v*>(reinterpret_cast<char*>(tile) +
                                (p << 12) + (wave << 10) + (l << 4)) = v;
#endif
  }
}

// NT GEMM, bf16 inputs: C[M][N] = A[M][K] * B[N][K]^T. Tile BM x 128, BK=64.
// EPI: 0 -> store bf16, 1 -> store f32, 2 -> store f32 with scale + mask.
template <int BM, int EPI>
__global__ __launch_bounds__(256) void gemm_bf16(
    const unsigned short* __restrict__ A, const unsigned short* __restrict__ B,
    void* __restrict__ Cout, int M, int N, int K,
    long aBatch, long bBatch, long cBatch,
    const int* __restrict__ srcMask, const int* __restrict__ melMask,
    float scale) {
  constexpr int NI = BM / 32;          // A-frags per wave (wave tile BM/2 x 64)
  __shared__ unsigned short As[BM * 64];
  __shared__ unsigned short Bs[128 * 64];
  const int tid = threadIdx.x;
  const int lane = tid & 63;
  const int wave = tid >> 6;
  const int z = blockIdx.z;
  const unsigned short* Ab = A + (long)z * aBatch;
  const unsigned short* Bb = B + (long)z * bBatch;
  const long cOff = (long)z * cBatch;
  const int bm = blockIdx.y * BM;
  const int bn = blockIdx.x * 128;
  const int wr = (wave >> 1) * (BM / 2);
  const int wc = (wave & 1) * 64;
  const int l15 = lane & 15;
  const int lHi = lane >> 4;

  f32x4 acc[NI][4] = {};

  for (int kt = 0; kt < K; kt += 64) {
    stage<BM / 32>(Ab + (long)bm * K + kt, K, As, tid);
    stage<4>(Bb + (long)bn * K + kt, K, Bs, tid);
    __syncthreads();
#pragma unroll
    for (int ks = 0; ks < 2; ++ks) {
      const int k0 = (ks << 5) + (lHi << 3);
      short8v af[NI], bfr[4];
#pragma unroll
      for (int i = 0; i < NI; ++i)
        af[i] = *reinterpret_cast<const short8v*>(
            reinterpret_cast<const char*>(As) + swz_byte(wr + i * 16 + l15, k0));
#pragma unroll
      for (int j = 0; j < 4; ++j)
        bfr[j] = *reinterpret_cast<const short8v*>(
            reinterpret_cast<const char*>(Bs) + swz_byte(wc + j * 16 + l15, k0));
#pragma unroll
      for (int i = 0; i < NI; ++i)
#pragma unroll
        for (int j = 0; j < 4; ++j)
          acc[i][j] = __builtin_amdgcn_mfma_f32_16x16x32_bf16(af[i], bfr[j], acc[i][j], 0, 0, 0);
    }
    __syncthreads();
  }

#pragma unroll
  for (int i = 0; i < NI; ++i) {
#pragma unroll
    for (int j = 0; j < 4; ++j) {
      const int rb = bm + wr + i * 16 + lHi * 4;
      const int c = bn + wc + j * 16 + l15;
#pragma unroll
      for (int r = 0; r < 4; ++r) {
        const float v = acc[i][j][r];
        const long idx = cOff + (long)(rb + r) * N + c;
        if constexpr (EPI == 0) {
          reinterpret_cast<unsigned short*>(Cout)[idx] = f2bf(v);
        } else if constexpr (EPI == 1) {
          reinterpret_cast<float*>(Cout)[idx] = v;
        } else {
          const bool sm = srcMask[z * 1024 + (rb + r)] != 0;
          const bool mm = melMask[z * 2048 + c] != 0;
          reinterpret_cast<float*>(Cout)[idx] = (sm && mm) ? -1e30f : v * scale;
        }
      }
    }
  }
}

// fp32 -> bf16 elementwise, 8 elems/thread, grid-stride.
__global__ __launch_bounds__(256) void f32_to_bf16(
    const float* __restrict__ in, unsigned short* __restrict__ out, long n) {
  long i = ((long)blockIdx.x * blockDim.x + threadIdx.x) * 8;
  const long stride = (long)gridDim.x * blockDim.x * 8;
  for (; i < n; i += stride) {
    const float4 a = *reinterpret_cast<const float4*>(in + i);
    const float4 b = *reinterpret_cast<const float4*>(in + i + 4);
    short8v o;
    o[0] = (short)f2bf(a.x); o[1] = (short)f2bf(a.y);
    o[2] = (short)f2bf(a.z); o[3] = (short)f2bf(a.w);
    o[4] = (short)f2bf(b.x); o[5] = (short)f2bf(b.y);
    o[6] = (short)f2bf(b.z); o[7] = (short)f2bf(b.w);
    *reinterpret_cast<short8v*>(out + i) = o;
  }
}

// Transpose+convert the three 512x512 fp32 weights to bf16 W^T.
__global__ __launch_bounds__(256) void transpose_w3(
    const float* __restrict__ Wq, const float* __restrict__ Wk, const float* __restrict__ Wv,
    unsigned short* __restrict__ WqT, unsigned short* __restrict__ WkT,
    unsigned short* __restrict__ WvT) {
  __shared__ float t[32][33];
  const int zz = blockIdx.z;
  const float* W = zz == 0 ? Wq : zz == 1 ? Wk : Wv;
  unsigned short* WT = zz == 0 ? WqT : zz == 1 ? WkT : WvT;
  const int bx = blockIdx.x * 32;
  const int by = blockIdx.y * 32;
  const int tx = threadIdx.x, ty = threadIdx.y;  // (32,8)
#pragma unroll
  for (int i = 0; i < 4; ++i)
    t[ty + i * 8][tx] = W[(long)(by + ty + i * 8) * 512 + bx + tx];
  __syncthreads();
#pragma unroll
  for (int i = 0; i < 4; ++i)
    WT[(long)(bx + ty + i * 8) * 512 + by + tx] = f2bf(t[tx][ty + i * 8]);
}

// In-place softmax over rows of 2048 fp32; also emits bf16 copy of P.
__global__ __launch_bounds__(256) void softmax_rows(
    float* __restrict__ attn, unsigned short* __restrict__ pbf) {
  const long row = blockIdx.x;
  float4* p = reinterpret_cast<float4*>(attn + row * 2048);
  const int tid = threadIdx.x;
  float4 a = p[tid];
  float4 b = p[tid + 256];
  float m = fmaxf(fmaxf(fmaxf(a.x, a.y), fmaxf(a.z, a.w)),
                  fmaxf(fmaxf(b.x, b.y), fmaxf(b.z, b.w)));
#pragma unroll
  for (int o = 32; o; o >>= 1) m = fmaxf(m, __shfl_xor(m, o, 64));
  __shared__ float redm[4];
  if ((tid & 63) == 0) redm[tid >> 6] = m;
  __syncthreads();
  m = fmaxf(fmaxf(redm[0], redm[1]), fmaxf(redm[2], redm[3]));
  float e0 = __expf(a.x - m), e1 = __expf(a.y - m), e2 = __expf(a.z - m), e3 = __expf(a.w - m);
  float e4 = __expf(b.x - m), e5 = __expf(b.y - m), e6 = __expf(b.z - m), e7 = __expf(b.w - m);
  float s = ((e0 + e1) + (e2 + e3)) + ((e4 + e5) + (e6 + e7));
#pragma unroll
  for (int o = 32; o; o >>= 1) s += __shfl_xor(s, o, 64);
  __shared__ float reds[4];
  if ((tid & 63) == 0) reds[tid >> 6] = s;
  __syncthreads();
  s = (reds[0] + reds[1]) + (reds[2] + reds[3]);
  const float inv = 1.0f / s;
  a.x = e0 * inv; a.y = e1 * inv; a.z = e2 * inv; a.w = e3 * inv;
  b.x = e4 * inv; b.y = e5 * inv; b.z = e6 * inv; b.w = e7 * inv;
  p[tid] = a;
  p[tid + 256] = b;
  ushort4 o0, o1;
  o0.x = f2bf(a.x); o0.y = f2bf(a.y); o0.z = f2bf(a.z); o0.w = f2bf(a.w);
  o1.x = f2bf(b.x); o1.y = f2bf(b.y); o1.z = f2bf(b.z); o1.w = f2bf(b.w);
  *reinterpret_cast<ushort4*>(pbf + row * 2048 + tid * 4) = o0;
  *reinterpret_cast<ushort4*>(pbf + row * 2048 + 1024 + tid * 4) = o1;
}

// In-place LayerNorm over rows of 512 fp32. One wave per row.
__global__ __launch_bounds__(64) void layernorm_rows(
    float* __restrict__ out, const float* __restrict__ gamma, const float* __restrict__ beta) {
  const long row = blockIdx.x;
  float4* p = reinterpret_cast<float4*>(out + row * 512);
  const int lane = threadIdx.x;
  float4 a = p[lane];
  float4 b = p[lane + 64];
  float s = ((a.x + a.y) + (a.z + a.w)) + ((b.x + b.y) + (b.z + b.w));
  float s2 = ((a.x * a.x + a.y * a.y) + (a.z * a.z + a.w * a.w)) +
             ((b.x * b.x + b.y * b.y) + (b.z * b.z + b.w * b.w));
#pragma unroll
  for (int o = 32; o; o >>= 1) {
    s += __shfl_xor(s, o, 64);
    s2 += __shfl_xor(s2, o, 64);
  }
  const float mean = s * (1.0f / 512.0f);
  const float var = s2 * (1.0f / 512.0f) - mean * mean;
  const float rstd = rsqrtf(var + 1e-5f);
  const float4 g0 = reinterpret_cast<const float4*>(gamma)[lane];
  const float4 g1 = reinterpret_cast<const float4*>(gamma)[lane + 64];
  const float4 c0 = reinterpret_cast<const float4*>(beta)[lane];
  const float4 c1 = reinterpret_cast<const float4*>(beta)[lane + 64];
  a.x = (a.x - mean) * rstd * g0.x + c0.x;
  a.y = (a.y - mean) * rstd * g0.y + c0.y;
  a.z = (a.z - mean) * rstd * g0.z + c0.z;
  a.w = (a.w - mean) * rstd * g0.w + c0.w;
  b.x = (b.x - mean) * rstd * g1.x + c1.x;
  b.y = (b.y - mean) * rstd * g1.y + c1.y;
  b.z = (b.z - mean) * rstd * g1.z + c1.z;
  b.w = (b.w - mean) * rstd * g1.w + c1.w;
  p[lane] = a;
  p[lane + 64] = b;
}

extern "C" void kernel_launch(void* const* d_in, const int* in_sizes, int n_in,
                              void* d_out, int out_size, void* d_ws, size_t ws_size,
                              hipStream_t stream) {
  const float* mel  = (const float*)d_in[0];   // [16,2048,512]
  const float* text = (const float*)d_in[1];   // [16,1024,512]
  const int* melMask = (const int*)d_in[2];    // [16,2048]
  const int* srcMask = (const int*)d_in[3];    // [16,1024]
  const float* Wq = (const float*)d_in[4];
  const float* Wk = (const float*)d_in[5];
  const float* Wv = (const float*)d_in[6];
  const float* gamma = (const float*)d_in[7];
  const float* beta  = (const float*)d_in[8];

  float* out = (float*)d_out;                           // [16,1024,512]
  float* attn = (float*)d_out + (long)16 * 1024 * 512;  // [16,1024,2048]

  unsigned short* ws = (unsigned short*)d_ws;
  unsigned short* wqT = ws;                               // 512*512
  unsigned short* wkT = wqT + 512 * 512;
  unsigned short* wvT = wkT + 512 * 512;
  unsigned short* melbf  = wvT + 512 * 512;               // 16*2048*512
  unsigned short* textbf = melbf + (long)16 * 2048 * 512; // 16*1024*512
  unsigned short* qbf = textbf + (long)16 * 1024 * 512;   // 16*1024*512
  unsigned short* kbf = qbf + (long)16 * 1024 * 512;      // 16*2048*512
  unsigned short* vT  = kbf + (long)16 * 2048 * 512;      // 16*512*2048
  // P (bf16) aliases melbf+textbf+qbf (exactly 16*1024*2048 elements),
  // all dead by the time softmax writes it.
  unsigned short* pbf = melbf;

  transpose_w3<<<dim3(16, 16, 3), dim3(32, 8), 0, stream>>>(Wq, Wk, Wv, wqT, wkT, wvT);
  f32_to_bf16<<<dim3(4096), 256, 0, stream>>>(mel, melbf, (long)16 * 2048 * 512);
  f32_to_bf16<<<dim3(2048), 256, 0, stream>>>(text, textbf, (long)16 * 1024 * 512);

  // q = text @ Wq   (bf16 out)
  gemm_bf16<128, 0><<<dim3(4, 128, 1), 256, 0, stream>>>(
      textbf, wqT, qbf, 16384, 512, 512, 0, 0, 0, nullptr, nullptr, 1.0f);
  // k = mel @ Wk
  gemm_bf16<128, 0><<<dim3(4, 256, 1), 256, 0, stream>>>(
      melbf, wkT, kbf, 32768, 512, 512, 0, 0, 0, nullptr, nullptr, 1.0f);
  // vT[b][m][s] = Wv^T[m][:] . mel[b][s][:]
  gemm_bf16<128, 0><<<dim3(16, 4, 16), 256, 0, stream>>>(
      wvT, melbf, vT, 512, 2048, 512, 0, (long)2048 * 512, (long)512 * 2048,
      nullptr, nullptr, 1.0f);
  // raw masked scores (fp32) -> attn region
  gemm_bf16<128, 2><<<dim3(16, 8, 16), 256, 0, stream>>>(
      qbf, kbf, attn, 1024, 2048, 512,
      (long)1024 * 512, (long)2048 * 512, (long)1024 * 2048,
      srcMask, melMask, 0.044194173824159216f);
  // softmax rows in place + bf16 P
  softmax_rows<<<dim3(16 * 1024), 256, 0, stream>>>(attn, pbf);
  // out = P @ v   (64-row tiles -> 1024 blocks)
  gemm_bf16<64, 1><<<dim3(4, 16, 16), 256, 0, stream>>>(
      pbf, vT, out, 1024, 512, 2048,
      (long)1024 * 2048, (long)512 * 2048, (long)1024 * 512,
      nullptr, nullptr, 1.0f);
  layernorm_rows<<<dim3(16 * 1024), 64, 0, stream>>>(out, gamma, beta);
}